// Round 13
// baseline (120.982 us; speedup 1.0000x reference)
//
#include <hip/hip_runtime.h>
#include <math.h>

// Problem: X[16384,64] fp32, W[8192,64] fp32 -> argmin_c ||x-w_c||^2 (int32)
#define EMB     64
#define NTOK    8192
#define NQ      16384
#define TPB     256               // 4 waves: 2 q-halves x 2 c-halves
#define CSPLIT  8
#define CRANGE  (NTOK / CSPLIT)   // 1024 codewords per y-split
#define BQ      128               // query rows per block
#define TILE_C  128               // codewords per iteration (FULL size -- r10's
                                  // 4-blk/CU test halved this; confounded)
#define NT      (CRANGE / TILE_C) // 8 tiles
#define TCH     (TILE_C * EMB)    // halves per Wh tile buffer (8192 = 16KB)
#define NXBLK   (NQ / BQ)         // 128

typedef _Float16 half8 __attribute__((ext_vector_type(8)));
typedef float    f32x4 __attribute__((ext_vector_type(4)));

// async global->LDS DMA, 16B per lane (dest = wave-uniform base + lane*16)
__device__ __forceinline__ void gl2lds16(const _Float16* g, _Float16* l) {
    __builtin_amdgcn_global_load_lds(
        (const __attribute__((address_space(1))) unsigned int*)g,
        (__attribute__((address_space(3))) unsigned int*)l, 16, 0, 0);
}

// monotone float->uint map: m(a) < m(b) iff a < b (no NaNs here)
__device__ __forceinline__ unsigned long long pack_di(float d, int idx) {
    unsigned int u = __float_as_uint(d);
    unsigned int m = (u & 0x80000000u) ? ~u : (u | 0x80000000u);
    return ((unsigned long long)m << 32) | (unsigned int)idx;
}

// ---------------------------------------------------------------------------
// Prep v3 (verified r11/r12) -- COALESCED. One thread per input 8-float
// segment (65536 threads): reads row c = gtid>>3, seg = gtid&7 (wave covers
// contiguous 2KB). Writes Wh/Wl in MFMA-FRAGMENT ORDER (bit-identical bytes
// to the r5-r12-verified layout):
//   chunk u = g*128 + kb*64 + lq*16 + r holds W[g*16+r][kb*32+lq*8..+7].
// ynorm via 3-step shfl_xor tree over the 8 same-row lanes.
// Also inits packed[]/cnt[].
// ---------------------------------------------------------------------------
__global__ void prep_kernel(const float* __restrict__ W,
                            _Float16* __restrict__ Wh, _Float16* __restrict__ Wl,
                            float* __restrict__ ynorm,
                            unsigned long long* __restrict__ packed,
                            int* __restrict__ cnt) {
    const int gtid = blockIdx.x * blockDim.x + threadIdx.x;   // 0..65535
    if (gtid < NQ)    packed[gtid] = ~0ull;
    if (gtid < NXBLK) cnt[gtid] = 0;

    const int c   = gtid >> 3;          // input row (0..8191)
    const int seg = gtid & 7;           // 8-float segment within row
    const float* wp = W + (size_t)c * EMB + seg * 8;
    float4 v0 = *(const float4*)wp;     // coalesced: wave covers 2KB contiguous
    float4 v1 = *(const float4*)(wp + 4);
    float xv[8] = {v0.x, v0.y, v0.z, v0.w, v1.x, v1.y, v1.z, v1.w};
    half8 h, l;
    float s8 = 0.f;
#pragma unroll
    for (int j = 0; j < 8; ++j) {
        _Float16 hh = (_Float16)xv[j];
        h[j] = hh;
        l[j] = (_Float16)(xv[j] - (float)hh);
        s8 = fmaf(xv[j], xv[j], s8);
    }
    const int g = c >> 4, r = c & 15, kb = seg >> 2, lq = seg & 3;
    const size_t u = (size_t)g * 128 + kb * 64 + lq * 16 + r;
    *(half8*)(Wh + u * 8) = h;
    *(half8*)(Wl + u * 8) = l;

    // ynorm: tree-sum the 8 segment partials of row c (lanes 8-aligned)
    s8 += __shfl_xor(s8, 1, 64);
    s8 += __shfl_xor(s8, 2, 64);
    s8 += __shfl_xor(s8, 4, 64);
    if (seg == 0) ynorm[c] = s8;
}

// ---------------------------------------------------------------------------
// Main: r12 numerics (3-term fp16 split, -2 prescale, yn-fold acc-init,
// verified absmax=0) at 4 BLOCKS/CU with FULL 128-tiles -- the
// un-confounded occupancy test:
//  - Wl in REGISTERS (blr[4][2], r7-proven bit-identical path) -> no Wl LDS.
//  - Wh shared 2-deep LDS tile (2x16KB) + Lyn 4KB + red 2.5KB = ~38.5KB
//    -> 4 blocks/CU; CSPLIT=8 -> grid 1024 = 4/CU x 256 CU.
//  - r6 sync (stage(t+1) -> compute(t) -> vmcnt(0)+lgkm(0)+barrier).
// Session ledger (measured -- do not regress):
//  - __launch_bounds__ arg2: 3 -> cap ~170 ok; 2 -> ~128 ok; >=4 -> 64 VGPR
//    = total spill (r2, r9).
//  - coop grid.sync fusion 3x slower (r4); __threadfence finisher +34us (r5).
//  - sync ablation r6/r7/r8 all ~66us; r10 (4blk/CU but HALF-tiles) 77us.
//  - yn-fold (r12): 66 -> 62us. total-vs-main gap ~47us = fixed harness OH.
// ---------------------------------------------------------------------------
__global__ __launch_bounds__(TPB, 2) void vq_mfma_kernel(
    const float* __restrict__ X,
    const _Float16* __restrict__ Wh, const _Float16* __restrict__ Wl,
    const float* __restrict__ ynorm,
    unsigned long long* __restrict__ packed,
    int* __restrict__ cnt, int* __restrict__ out)
{
    __shared__ __align__(16) _Float16 LdsH0[TCH];   // 16KB
    __shared__ __align__(16) _Float16 LdsH1[TCH];   // 16KB
    __shared__ __align__(16) float    Lyn[CRANGE];  // 4KB
    __shared__ float RedV[2][BQ];
    __shared__ int   RedI[2][BQ];
    __shared__ int   fin;

    const int t    = threadIdx.x;
    const int lane = t & 63;
    const int wid  = t >> 6;       // 0..3
    const int wq   = wid & 1;      // q half (0/1)
    const int wy   = wid >> 1;     // c half (0/1)
    const int l15  = lane & 15;
    const int lq   = lane >> 4;    // 0..3

    const int bx     = blockIdx.x;
    const int qblk   = bx * BQ;
    const int qbase  = qblk + wq * 64;
    const int cbase0 = blockIdx.y * CRANGE;

    // --- issue tile-0 Wh DMA first so it overlaps prologue work ---
    {
        const size_t gsbase = (size_t)(cbase0 >> 4) * 1024;   // halves
#pragma unroll
        for (int i = 0; i < 4; ++i) {
            const int jw = i * 256 + wid * 64;                // wave-uniform chunk base
            gl2lds16(Wh + gsbase + (size_t)(jw + lane) * 8, LdsH0 + (size_t)jw * 8);
        }
    }

    // --- stage the block's full ynorm range once ---
    for (int u = t; u < CRANGE / 4; u += TPB)
        ((float4*)Lyn)[u] = ((const float4*)(ynorm + cbase0))[u];

    // --- A fragments PRE-SCALED by -2 (exact): X rows (qbase + mt*16 + l15),
    //     k = kb*32 + lq*8 + j. Products become -2*x*w; acc init = yn. ---
    half8 ah[4][2], al[4][2];
#pragma unroll
    for (int mt = 0; mt < 4; ++mt) {
#pragma unroll
        for (int kb = 0; kb < 2; ++kb) {
            const float* xp = X + (size_t)(qbase + mt * 16 + l15) * EMB + kb * 32 + lq * 8;
            float4 v0 = *(const float4*)xp;
            float4 v1 = *(const float4*)(xp + 4);
            float xv[8] = {v0.x, v0.y, v0.z, v0.w, v1.x, v1.y, v1.z, v1.w};
            half8 h, l;
#pragma unroll
            for (int j = 0; j < 8; ++j) {
                _Float16 hh = (_Float16)xv[j];               // hi split (unscaled)
                float    rr = xv[j] - (float)hh;             // exact residual
                h[j] = (_Float16)(-2.0f * (float)hh);        // exact x2 scale
                l[j] = (_Float16)(-2.0f * rr);               // exact x2 scale
            }
            ah[mt][kb] = h;
            al[mt][kb] = l;
        }
    }

    float minv[4][4];
    int   mini[4][4];
#pragma unroll
    for (int mt = 0; mt < 4; ++mt)
#pragma unroll
        for (int r = 0; r < 4; ++r) { minv[mt][r] = INFINITY; mini[mt][r] = 0; }

    __syncthreads();   // tile0 DMA + Lyn writes visible

    int cur = 0;
    for (int tt = 0; tt < NT; ++tt) {
        const int cb = cbase0 + tt * TILE_C;

        // --- (1) Wl lo-fragments for THIS tile -> regs (8 vmem, this wave's
        //     c-half: groups (cb>>4)+wy*4+ct, chunk = g*128 + kb*64 + lane) ---
        half8 blr[4][2];
        {
            const size_t gchunk = ((size_t)(cb >> 4) + wy * 4) * 128 + lane;
#pragma unroll
            for (int ct = 0; ct < 4; ++ct) {
                blr[ct][0] = *(const half8*)(Wl + (gchunk + ct * 128) * 8);
                blr[ct][1] = *(const half8*)(Wl + (gchunk + ct * 128 + 64) * 8);
            }
        }

        // --- (2) STAGE Wh tile tt+1 into the other buffer (async DMA) ---
        if (tt + 1 < NT) {
            const size_t gsbase = (size_t)((cb + TILE_C) >> 4) * 1024;
            _Float16* dH = (cur ^ 1) ? LdsH1 : LdsH0;
#pragma unroll
            for (int i = 0; i < 4; ++i) {
                const int jw = i * 256 + wid * 64;
                gl2lds16(Wh + gsbase + (size_t)(jw + lane) * 8, dH + (size_t)jw * 8);
            }
        }

        // --- (3) COMPUTE tile tt: Wh from LDS buf cur, Wl from blr ---
        const _Float16* LH = cur ? LdsH1 : LdsH0;
        const int c0 = tt * TILE_C;
#pragma unroll
        for (int ct = 0; ct < 4; ++ct) {
            const int chunk0 = (wy * 4 + ct) * 128 + lane;   // 64 consecutive chunks/wave
            const int ccol   = wy * 64 + ct * 16;
            const float yn   = Lyn[c0 + ccol + l15];         // col depends on l15 only
            const f32x4 yn4  = {yn, yn, yn, yn};             // acc init = yn (D: col=lane&15)
            half8 bh0 = *(const half8*)(LH + (size_t)chunk0 * 8);
            half8 bh1 = *(const half8*)(LH + (size_t)(chunk0 + 64) * 8);
            f32x4 acc[4];
#pragma unroll
            for (int mt = 0; mt < 4; ++mt) {
                // 3-term x (-2) with yn-init: acc ends as dist directly
                f32x4 a = __builtin_amdgcn_mfma_f32_16x16x32_f16(al[mt][0], bh0, yn4, 0, 0, 0);
                a = __builtin_amdgcn_mfma_f32_16x16x32_f16(ah[mt][0], blr[ct][0], a, 0, 0, 0);
                a = __builtin_amdgcn_mfma_f32_16x16x32_f16(ah[mt][0], bh0, a, 0, 0, 0);
                a = __builtin_amdgcn_mfma_f32_16x16x32_f16(al[mt][1], bh1, a, 0, 0, 0);
                a = __builtin_amdgcn_mfma_f32_16x16x32_f16(ah[mt][1], blr[ct][1], a, 0, 0, 0);
                a = __builtin_amdgcn_mfma_f32_16x16x32_f16(ah[mt][1], bh1, a, 0, 0, 0);
                acc[mt] = a;
            }
            // --- epilogue: acc IS dist; running argmin (c ascending, strict <) ---
            const int cidx = cb + ccol + l15;
#pragma unroll
            for (int mt = 0; mt < 4; ++mt) {
#pragma unroll
                for (int r = 0; r < 4; ++r) {
                    float s = acc[mt][r];
                    if (s < minv[mt][r]) { minv[mt][r] = s; mini[mt][r] = cidx; }
                }
            }
        }

        // --- drain: tile tt+1 DMA has been landing under the MFMAs above ---
        asm volatile("s_waitcnt vmcnt(0)" ::: "memory");
        asm volatile("s_waitcnt lgkmcnt(0)" ::: "memory");
        __builtin_amdgcn_s_barrier();
        cur ^= 1;
    }

    // --- cross-lane: reduce over the 16 col-lanes (xor on low 4 lane bits) ---
#pragma unroll
    for (int mt = 0; mt < 4; ++mt) {
#pragma unroll
        for (int r = 0; r < 4; ++r) {
            float v = minv[mt][r];
            int   i = mini[mt][r];
#pragma unroll
            for (int m = 1; m <= 8; m <<= 1) {
                float ov = __shfl_xor(v, m, 64);
                int   oi = __shfl_xor(i, m, 64);
                if (ov < v || (ov == v && oi < i)) { v = ov; i = oi; }
            }
            if (l15 == 0) {
                int qoff = wq * 64 + mt * 16 + lq * 4 + r;   // row within block
                RedV[wy][qoff] = v;
                RedI[wy][qoff] = i;
            }
        }
    }
    __syncthreads();

    // --- combine c-halves, then FENCE-FREE cross-split combine via atomics ---
    if (t < BQ) {
        float v0 = RedV[0][t]; int i0 = RedI[0][t];
        float v1 = RedV[1][t]; int i1 = RedI[1][t];
        if (v1 < v0 || (v1 == v0 && i1 < i0)) { v0 = v1; i0 = i1; }
        atomicMin(&packed[qblk + t], pack_di(v0, i0));   // device-scope, coherent
    }
    // ensure this block's atomicMins are globally performed before the ticket
    asm volatile("s_waitcnt vmcnt(0)" ::: "memory");
    __syncthreads();
    if (t == 0) fin = (atomicAdd(&cnt[bx], 1) == CSPLIT - 1);
    __syncthreads();
    if (fin && t < BQ) {
        // atomic read-back (atomicMin with identity) -> final packed value
        unsigned long long v = atomicMin(&packed[qblk + t], ~0ull);
        out[qblk + t] = (int)(unsigned int)(v & 0xFFFFFFFFu);
    }
}

// ---------------------------------------------------------------------------
extern "C" void kernel_launch(void* const* d_in, const int* in_sizes, int n_in,
                              void* d_out, int out_size, void* d_ws, size_t ws_size,
                              hipStream_t stream) {
    const float* X = (const float*)d_in[0];   // [16384, 64]
    const float* W = (const float*)d_in[1];   // [8192, 64]

    // ws layout: Wh(1MB) | Wl(1MB) | ynorm(32KB) | packed(128KB) | cnt(512B)
    _Float16* Wh    = (_Float16*)d_ws;
    _Float16* Wl    = Wh + (size_t)NTOK * EMB;
    float*    ynorm = (float*)(Wl + (size_t)NTOK * EMB);
    unsigned long long* packed = (unsigned long long*)(ynorm + NTOK);
    int*      cnt   = (int*)(packed + NQ);
    int*      out   = (int*)d_out;

    prep_kernel<<<(NTOK * 8) / TPB, TPB, 0, stream>>>(W, Wh, Wl, ynorm, packed, cnt);
    dim3 grid(NXBLK, CSPLIT);
    vq_mfma_kernel<<<grid, TPB, 0, stream>>>(X, Wh, Wl, ynorm, packed, cnt, out);
}

// Round 14
// 119.338 us; speedup vs baseline: 1.0138x; 1.0138x over previous
//
#include <hip/hip_runtime.h>
#include <math.h>

// Problem: X[16384,64] fp32, W[8192,64] fp32 -> argmin_c ||x-w_c||^2 (int32)
#define EMB     64
#define NTOK    8192
#define NQ      16384
#define TPB     256               // 4 waves: 2 q-halves x 2 c-halves
#define CSPLIT  4
#define CRANGE  (NTOK / CSPLIT)   // 2048 codewords per y-split
#define BQ      128               // query rows per block
#define TILE_C  128               // codewords staged in LDS per iteration
#define NT      (CRANGE / TILE_C) // 16 tiles
#define TCH     (TILE_C * EMB)    // halves per tile buffer (8192 = 16KB)
#define NXBLK   (NQ / BQ)         // 128

typedef _Float16 half8  __attribute__((ext_vector_type(8)));
typedef float    f32x16 __attribute__((ext_vector_type(16)));

// async global->LDS DMA, 16B per lane (dest = wave-uniform base + lane*16)
__device__ __forceinline__ void gl2lds16(const _Float16* g, _Float16* l) {
    __builtin_amdgcn_global_load_lds(
        (const __attribute__((address_space(1))) unsigned int*)g,
        (__attribute__((address_space(3))) unsigned int*)l, 16, 0, 0);
}

// monotone float->uint map: m(a) < m(b) iff a < b (no NaNs here)
__device__ __forceinline__ unsigned long long pack_di(float d, int idx) {
    unsigned int u = __float_as_uint(d);
    unsigned int m = (u & 0x80000000u) ? ~u : (u | 0x80000000u);
    return ((unsigned long long)m << 32) | (unsigned int)idx;
}

// ---------------------------------------------------------------------------
// Prep v4 -- COALESCED, 32x32-fragment order. One thread per input 8-float
// segment (65536 threads): reads row c = gtid>>3, seg = gtid&7 (wave covers
// contiguous 2KB). Writes Wh/Wl in mfma_32x32x16 B-FRAGMENT ORDER:
//   B layout: col = lane&31, k = (lane>>5)*8 + j  [guide m74/m101 family]
//   chunk u = (c>>5)*256 + kstep*64 + khalf*32 + (c&31)
//     holds W[c][kstep*16 + khalf*8 .. +7], kstep=seg>>1, khalf=seg&1.
//   A wave reading (group-of-32 cols, kstep) reads 64 consecutive chunks ->
//   linear global_load_lds staging + stride-1 conflict-free ds_read_b128.
// ynorm via 3-step shfl_xor tree over the 8 same-row lanes.
// Also inits packed[]/cnt[].
// ---------------------------------------------------------------------------
__global__ void prep_kernel(const float* __restrict__ W,
                            _Float16* __restrict__ Wh, _Float16* __restrict__ Wl,
                            float* __restrict__ ynorm,
                            unsigned long long* __restrict__ packed,
                            int* __restrict__ cnt) {
    const int gtid = blockIdx.x * blockDim.x + threadIdx.x;   // 0..65535
    if (gtid < NQ)    packed[gtid] = ~0ull;
    if (gtid < NXBLK) cnt[gtid] = 0;

    const int c   = gtid >> 3;          // input row (0..8191)
    const int seg = gtid & 7;           // 8-float segment within row
    const float* wp = W + (size_t)c * EMB + seg * 8;
    float4 v0 = *(const float4*)wp;     // coalesced: wave covers 2KB contiguous
    float4 v1 = *(const float4*)(wp + 4);
    float xv[8] = {v0.x, v0.y, v0.z, v0.w, v1.x, v1.y, v1.z, v1.w};
    half8 h, l;
    float s8 = 0.f;
#pragma unroll
    for (int j = 0; j < 8; ++j) {
        _Float16 hh = (_Float16)xv[j];
        h[j] = hh;
        l[j] = (_Float16)(xv[j] - (float)hh);
        s8 = fmaf(xv[j], xv[j], s8);
    }
    const size_t u = (size_t)(c >> 5) * 256 + (seg >> 1) * 64
                   + (seg & 1) * 32 + (c & 31);
    *(half8*)(Wh + u * 8) = h;
    *(half8*)(Wl + u * 8) = l;

    // ynorm: tree-sum the 8 segment partials of row c (lanes 8-aligned)
    s8 += __shfl_xor(s8, 1, 64);
    s8 += __shfl_xor(s8, 2, 64);
    s8 += __shfl_xor(s8, 4, 64);
    if (seg == 0) ynorm[c] = s8;
}

// ---------------------------------------------------------------------------
// Main: r12 numerics (3-term fp16 split, -2 prescale, yn-fold) on the
// 32x32x16 MFMA shape: 48 MFMA/wave-tile (was 96), each ~8cyc at the
// BETTER measured rate (2382 vs 2075 TF) -> floor 24.8 -> ~21.6us, and
// half the issue slots (attacks the ~62% matrix-pipe idle; VALUBusy ~=
// MfmaUtil+5% all session -> non-MFMA VALU is only ~5%, not a target).
// Layouts (guide, HW-verified m74/m101): C/D col=lane&31,
// row=(reg&3)+8*(reg>>2)+4*(lane>>5); A row=lane&31, k=(lane>>5)*8+j;
// B col=lane&31, k=(lane>>5)*8+j.
// Session ledger (measured -- do not regress):
//  - launch_bounds arg2: waves/CU cap = arg2*TPB/64; VGPR cap = 512/(waves
//    per SIMD). (256,3)->170, (256,2)->256, >=4 waves/SIMD -> 64 = spill.
//  - coop grid.sync 3x slower (r4); __threadfence finisher +34us (r5).
//  - sync ablation r6/r7/r8 all ~66us; occupancy worse 3x (r3/r10/r13).
//  - yn-fold r12: 66->62us (best). total-vs-main ~47us = fixed harness OH.
// ---------------------------------------------------------------------------
__global__ __launch_bounds__(TPB, 2) void vq_mfma_kernel(
    const float* __restrict__ X,
    const _Float16* __restrict__ Wh, const _Float16* __restrict__ Wl,
    const float* __restrict__ ynorm,
    unsigned long long* __restrict__ packed,
    int* __restrict__ cnt, int* __restrict__ out)
{
    __shared__ __align__(16) _Float16 LdsH0[TCH];
    __shared__ __align__(16) _Float16 LdsH1[TCH];
    __shared__ __align__(16) _Float16 LdsL0[TCH];
    __shared__ __align__(16) _Float16 LdsL1[TCH];
    __shared__ __align__(16) float    Lyn[CRANGE];
    __shared__ float RedV[2][BQ];
    __shared__ int   RedI[2][BQ];
    __shared__ int   fin;

    const int t    = threadIdx.x;
    const int lane = t & 63;
    const int wid  = t >> 6;       // 0..3
    const int wq   = wid & 1;      // q half (0/1)
    const int wy   = wid >> 1;     // c half (0/1)
    const int l31  = lane & 31;
    const int lh   = lane >> 5;    // k-half selector in A/B frags

    const int bx     = blockIdx.x;
    const int qblk   = bx * BQ;
    const int qbase  = qblk + wq * 64;
    const int cbase0 = blockIdx.y * CRANGE;

    // --- issue tile-0 DMA first so it overlaps prologue work ---
    {
        const size_t gsbase = (size_t)cbase0 * 64;            // halves (=chunks*8)
#pragma unroll
        for (int i = 0; i < 4; ++i) {
            const int jw = i * 256 + wid * 64;                // wave-uniform chunk base
            gl2lds16(Wh + gsbase + (size_t)(jw + lane) * 8, LdsH0 + (size_t)jw * 8);
            gl2lds16(Wl + gsbase + (size_t)(jw + lane) * 8, LdsL0 + (size_t)jw * 8);
        }
    }

    // --- stage the block's full ynorm range once ---
    for (int u = t; u < CRANGE / 4; u += TPB)
        ((float4*)Lyn)[u] = ((const float4*)(ynorm + cbase0))[u];

    // --- A fragments PRE-SCALED by -2 (exact): row = qbase + mtile*32 + l31,
    //     k = ks*16 + lh*8 + j. ---
    half8 ah[2][4], al[2][4];
#pragma unroll
    for (int mtile = 0; mtile < 2; ++mtile) {
#pragma unroll
        for (int ks = 0; ks < 4; ++ks) {
            const float* xp = X + (size_t)(qbase + mtile * 32 + l31) * EMB
                            + ks * 16 + lh * 8;
            float4 v0 = *(const float4*)xp;
            float4 v1 = *(const float4*)(xp + 4);
            float xv[8] = {v0.x, v0.y, v0.z, v0.w, v1.x, v1.y, v1.z, v1.w};
            half8 h, l;
#pragma unroll
            for (int j = 0; j < 8; ++j) {
                _Float16 hh = (_Float16)xv[j];               // hi split (unscaled)
                float    rr = xv[j] - (float)hh;             // exact residual
                h[j] = (_Float16)(-2.0f * (float)hh);        // exact x2 scale
                l[j] = (_Float16)(-2.0f * rr);               // exact x2 scale
            }
            ah[mtile][ks] = h;
            al[mtile][ks] = l;
        }
    }

    float minv[2][16];
    int   mini[2][16];
#pragma unroll
    for (int mtile = 0; mtile < 2; ++mtile)
#pragma unroll
        for (int r = 0; r < 16; ++r) { minv[mtile][r] = INFINITY; mini[mtile][r] = 0; }

    __syncthreads();   // tile0 DMA + Lyn writes visible

    int cur = 0;
    for (int tt = 0; tt < NT; ++tt) {
        const int cb = cbase0 + tt * TILE_C;

        // --- STAGE tile tt+1 into the other buffer (async DMA, in flight under MFMAs) ---
        if (tt + 1 < NT) {
            const size_t gsbase = (size_t)(cb + TILE_C) * 64;
            _Float16* dH = (cur ^ 1) ? LdsH1 : LdsH0;
            _Float16* dL = (cur ^ 1) ? LdsL1 : LdsL0;
#pragma unroll
            for (int i = 0; i < 4; ++i) {
                const int jw = i * 256 + wid * 64;
                gl2lds16(Wh + gsbase + (size_t)(jw + lane) * 8, dH + (size_t)jw * 8);
                gl2lds16(Wl + gsbase + (size_t)(jw + lane) * 8, dL + (size_t)jw * 8);
            }
        }

        // --- COMPUTE tile tt from buf cur ---
        const _Float16* LH = cur ? LdsH1 : LdsH0;
        const _Float16* LL = cur ? LdsL1 : LdsL0;
        const int c0 = tt * TILE_C;
#pragma unroll
        for (int ctile = 0; ctile < 2; ++ctile) {
            // B frags: tile-local chunk (wy*2+ctile)*256 + ks*64 + lane
            const int cbase = (wy * 2 + ctile) * 256 + lane;
            half8 bh[4], bl[4];
#pragma unroll
            for (int ks = 0; ks < 4; ++ks) {
                bh[ks] = *(const half8*)(LH + (size_t)(cbase + ks * 64) * 8);
                bl[ks] = *(const half8*)(LL + (size_t)(cbase + ks * 64) * 8);
            }
            const int   ccol = wy * 64 + ctile * 32;
            const float yn   = Lyn[c0 + ccol + l31];        // C col = lane&31
            const int   cidx = cb + ccol + l31;
            f32x16 yn16;
#pragma unroll
            for (int r = 0; r < 16; ++r) yn16[r] = yn;      // acc init = yn
#pragma unroll
            for (int mtile = 0; mtile < 2; ++mtile) {
                f32x16 a = yn16;
#pragma unroll
                for (int ks = 0; ks < 4; ++ks) {
                    // 3-term x (-2) with yn-init: acc ends as dist directly
                    a = __builtin_amdgcn_mfma_f32_32x32x16_f16(al[mtile][ks], bh[ks], a, 0, 0, 0);
                    a = __builtin_amdgcn_mfma_f32_32x32x16_f16(ah[mtile][ks], bl[ks], a, 0, 0, 0);
                    a = __builtin_amdgcn_mfma_f32_32x32x16_f16(ah[mtile][ks], bh[ks], a, 0, 0, 0);
                }
                // --- epilogue: a IS dist; running argmin (c ascending, strict <) ---
#pragma unroll
                for (int r = 0; r < 16; ++r) {
                    float s = a[r];
                    if (s < minv[mtile][r]) { minv[mtile][r] = s; mini[mtile][r] = cidx; }
                }
            }
        }

        // --- drain: tile tt+1 DMA has been landing under the MFMAs above ---
        asm volatile("s_waitcnt vmcnt(0)" ::: "memory");
        asm volatile("s_waitcnt lgkmcnt(0)" ::: "memory");
        __builtin_amdgcn_s_barrier();
        cur ^= 1;
    }

    // --- cross-lane: reduce over the 32 col-lanes (xor on low 5 lane bits) ---
#pragma unroll
    for (int mtile = 0; mtile < 2; ++mtile) {
#pragma unroll
        for (int r = 0; r < 16; ++r) {
            float v = minv[mtile][r];
            int   i = mini[mtile][r];
#pragma unroll
            for (int m = 1; m <= 16; m <<= 1) {
                float ov = __shfl_xor(v, m, 64);
                int   oi = __shfl_xor(i, m, 64);
                if (ov < v || (ov == v && oi < i)) { v = ov; i = oi; }
            }
            if (l31 == 0) {
                // C row = (r&3) + 8*(r>>2) + 4*lh; lanes 0 and 32 hold
                // different rows -> no write conflict
                int qoff = wq * 64 + mtile * 32 + (r & 3) + 8 * (r >> 2) + 4 * lh;
                RedV[wy][qoff] = v;
                RedI[wy][qoff] = i;
            }
        }
    }
    __syncthreads();

    // --- combine c-halves, then FENCE-FREE cross-split combine via atomics ---
    if (t < BQ) {
        float v0 = RedV[0][t]; int i0 = RedI[0][t];
        float v1 = RedV[1][t]; int i1 = RedI[1][t];
        if (v1 < v0 || (v1 == v0 && i1 < i0)) { v0 = v1; i0 = i1; }
        atomicMin(&packed[qblk + t], pack_di(v0, i0));   // device-scope, coherent
    }
    // ensure this block's atomicMins are globally performed before the ticket
    asm volatile("s_waitcnt vmcnt(0)" ::: "memory");
    __syncthreads();
    if (t == 0) fin = (atomicAdd(&cnt[bx], 1) == CSPLIT - 1);
    __syncthreads();
    if (fin && t < BQ) {
        // atomic read-back (atomicMin with identity) -> final packed value
        unsigned long long v = atomicMin(&packed[qblk + t], ~0ull);
        out[qblk + t] = (int)(unsigned int)(v & 0xFFFFFFFFu);
    }
}

// ---------------------------------------------------------------------------
extern "C" void kernel_launch(void* const* d_in, const int* in_sizes, int n_in,
                              void* d_out, int out_size, void* d_ws, size_t ws_size,
                              hipStream_t stream) {
    const float* X = (const float*)d_in[0];   // [16384, 64]
    const float* W = (const float*)d_in[1];   // [8192, 64]

    // ws layout: Wh(1MB) | Wl(1MB) | ynorm(32KB) | packed(128KB) | cnt(512B)
    _Float16* Wh    = (_Float16*)d_ws;
    _Float16* Wl    = Wh + (size_t)NTOK * EMB;
    float*    ynorm = (float*)(Wl + (size_t)NTOK * EMB);
    unsigned long long* packed = (unsigned long long*)(ynorm + NTOK);
    int*      cnt   = (int*)(packed + NQ);
    int*      out   = (int*)d_out;

    prep_kernel<<<(NTOK * 8) / TPB, TPB, 0, stream>>>(W, Wh, Wl, ynorm, packed, cnt);
    dim3 grid(NXBLK, CSPLIT);
    vq_mfma_kernel<<<grid, TPB, 0, stream>>>(X, Wh, Wl, ynorm, packed, cnt, out);
}

// Round 15
// 111.626 us; speedup vs baseline: 1.0838x; 1.0691x over previous
//
#include <hip/hip_runtime.h>
#include <math.h>

// Problem: X[16384,64] fp32, W[8192,64] fp32 -> argmin_c ||x-w_c||^2 (int32)
#define EMB     64
#define NTOK    8192
#define NQ      16384
#define TPB     256               // 4 waves: 2 q-halves x 2 c-halves
#define CSPLIT  4
#define CRANGE  (NTOK / CSPLIT)   // 2048 codewords per y-split
#define BQ      128               // query rows per block
#define TILE_C  128               // codewords staged in LDS per iteration
#define NT      (CRANGE / TILE_C) // 16 tiles
#define TCH     (TILE_C * EMB)    // halves per tile buffer (8192 = 16KB)
#define NXBLK   (NQ / BQ)         // 128

typedef _Float16 half8 __attribute__((ext_vector_type(8)));
typedef float    f32x4 __attribute__((ext_vector_type(4)));

// async global->LDS DMA, 16B per lane (dest = wave-uniform base + lane*16)
__device__ __forceinline__ void gl2lds16(const _Float16* g, _Float16* l) {
    __builtin_amdgcn_global_load_lds(
        (const __attribute__((address_space(1))) unsigned int*)g,
        (__attribute__((address_space(3))) unsigned int*)l, 16, 0, 0);
}

// monotone float->uint map: m(a) < m(b) iff a < b (no NaNs here)
__device__ __forceinline__ unsigned long long pack_di(float d, int idx) {
    unsigned int u = __float_as_uint(d);
    unsigned int m = (u & 0x80000000u) ? ~u : (u | 0x80000000u);
    return ((unsigned long long)m << 32) | (unsigned int)idx;
}

// ---------------------------------------------------------------------------
// Prep v3 (verified r11/r12) -- COALESCED. One thread per input 8-float
// segment (65536 threads): reads row c = gtid>>3, seg = gtid&7 (wave covers
// contiguous 2KB). Writes Wh/Wl in 16x16 MFMA-FRAGMENT ORDER (bit-identical
// bytes to the r5-r12-verified layout):
//   chunk u = g*128 + kb*64 + lq*16 + r holds W[g*16+r][kb*32+lq*8..+7].
// ynorm via 3-step shfl_xor tree over the 8 same-row lanes.
// Also inits packed[]/cnt[].
// ---------------------------------------------------------------------------
__global__ void prep_kernel(const float* __restrict__ W,
                            _Float16* __restrict__ Wh, _Float16* __restrict__ Wl,
                            float* __restrict__ ynorm,
                            unsigned long long* __restrict__ packed,
                            int* __restrict__ cnt) {
    const int gtid = blockIdx.x * blockDim.x + threadIdx.x;   // 0..65535
    if (gtid < NQ)    packed[gtid] = ~0ull;
    if (gtid < NXBLK) cnt[gtid] = 0;

    const int c   = gtid >> 3;          // input row (0..8191)
    const int seg = gtid & 7;           // 8-float segment within row
    const float* wp = W + (size_t)c * EMB + seg * 8;
    float4 v0 = *(const float4*)wp;     // coalesced: wave covers 2KB contiguous
    float4 v1 = *(const float4*)(wp + 4);
    float xv[8] = {v0.x, v0.y, v0.z, v0.w, v1.x, v1.y, v1.z, v1.w};
    half8 h, l;
    float s8 = 0.f;
#pragma unroll
    for (int j = 0; j < 8; ++j) {
        _Float16 hh = (_Float16)xv[j];
        h[j] = hh;
        l[j] = (_Float16)(xv[j] - (float)hh);
        s8 = fmaf(xv[j], xv[j], s8);
    }
    const int g = c >> 4, r = c & 15, kb = seg >> 2, lq = seg & 3;
    const size_t u = (size_t)g * 128 + kb * 64 + lq * 16 + r;
    *(half8*)(Wh + u * 8) = h;
    *(half8*)(Wl + u * 8) = l;

    // ynorm: tree-sum the 8 segment partials of row c (lanes 8-aligned)
    s8 += __shfl_xor(s8, 1, 64);
    s8 += __shfl_xor(s8, 2, 64);
    s8 += __shfl_xor(s8, 4, 64);
    if (seg == 0) ynorm[c] = s8;
}

// ---------------------------------------------------------------------------
// Main: r12 numerics (3-term fp16 split, -2 prescale, yn-fold acc-init,
// 16x16x32 shape -- all verified absmax=0, best measured 62us) with the
// inner loop restructured to the m201 FINE-PHASE template: per tile, 4
// phases of {ds_read this ct's frags; issue 2 of the 8 stage DMAs;
// sched_barrier; s_barrier; lgkmcnt(0)+sched_barrier; setprio(1); 24 MFMA;
// setprio(0); epilogue; s_barrier}. Mechanism (m196/m233): the barrier
// between a wave's ds_read issue and wait lets other waves' MFMA clusters
// cover the latency; setprio gets role diversity to arbitrate. Partial
// measures (drain removal r8, counted-wait r7) measured null -- the FULL
// interleave is the lever under test.
// Session ledger (measured -- do not regress):
//  - launch_bounds arg2: (256,3)->cap 170 ok; >=4 waves/SIMD -> 64 = spill.
//  - coop grid.sync 3x slower (r4); __threadfence finisher +34us (r5).
//  - sync ablation r6/r7/r8 all ~66; occupancy worse 3x (r3/r10/r13);
//    32x32 shape worse (r14: 77.5 -- 2x12-deep chains < 4x6-deep ILP).
//  - yn-fold r12: 66->62us (best). total-vs-main ~47us = fixed harness OH.
// ---------------------------------------------------------------------------
__global__ __launch_bounds__(TPB, 3) void vq_mfma_kernel(
    const float* __restrict__ X,
    const _Float16* __restrict__ Wh, const _Float16* __restrict__ Wl,
    const float* __restrict__ ynorm,
    unsigned long long* __restrict__ packed,
    int* __restrict__ cnt, int* __restrict__ out)
{
    __shared__ __align__(16) _Float16 LdsH0[TCH];
    __shared__ __align__(16) _Float16 LdsH1[TCH];
    __shared__ __align__(16) _Float16 LdsL0[TCH];
    __shared__ __align__(16) _Float16 LdsL1[TCH];
    __shared__ __align__(16) float    Lyn[CRANGE];
    __shared__ float RedV[2][BQ];
    __shared__ int   RedI[2][BQ];
    __shared__ int   fin;

    const int t    = threadIdx.x;
    const int lane = t & 63;
    const int wid  = t >> 6;       // 0..3
    const int wq   = wid & 1;      // q half (0/1)
    const int wy   = wid >> 1;     // c half (0/1)
    const int l15  = lane & 15;
    const int lq   = lane >> 4;    // 0..3

    const int bx     = blockIdx.x;
    const int qblk   = bx * BQ;
    const int qbase  = qblk + wq * 64;
    const int cbase0 = blockIdx.y * CRANGE;

    // --- issue tile-0 DMA first so it overlaps prologue work ---
    {
        const size_t gsbase = (size_t)(cbase0 >> 4) * 1024;   // halves
#pragma unroll
        for (int i = 0; i < 4; ++i) {
            const int jw = i * 256 + wid * 64;                // wave-uniform chunk base
            gl2lds16(Wh + gsbase + (size_t)(jw + lane) * 8, LdsH0 + (size_t)jw * 8);
            gl2lds16(Wl + gsbase + (size_t)(jw + lane) * 8, LdsL0 + (size_t)jw * 8);
        }
    }

    // --- stage the block's full ynorm range once ---
    for (int u = t; u < CRANGE / 4; u += TPB)
        ((float4*)Lyn)[u] = ((const float4*)(ynorm + cbase0))[u];

    // --- A fragments PRE-SCALED by -2 (exact): X rows (qbase + mt*16 + l15),
    //     k = kb*32 + lq*8 + j. Products become -2*x*w; acc init = yn. ---
    half8 ah[4][2], al[4][2];
#pragma unroll
    for (int mt = 0; mt < 4; ++mt) {
#pragma unroll
        for (int kb = 0; kb < 2; ++kb) {
            const float* xp = X + (size_t)(qbase + mt * 16 + l15) * EMB + kb * 32 + lq * 8;
            float4 v0 = *(const float4*)xp;
            float4 v1 = *(const float4*)(xp + 4);
            float xv[8] = {v0.x, v0.y, v0.z, v0.w, v1.x, v1.y, v1.z, v1.w};
            half8 h, l;
#pragma unroll
            for (int j = 0; j < 8; ++j) {
                _Float16 hh = (_Float16)xv[j];               // hi split (unscaled)
                float    rr = xv[j] - (float)hh;             // exact residual
                h[j] = (_Float16)(-2.0f * (float)hh);        // exact x2 scale
                l[j] = (_Float16)(-2.0f * rr);               // exact x2 scale
            }
            ah[mt][kb] = h;
            al[mt][kb] = l;
        }
    }

    float minv[4][4];
    int   mini[4][4];
#pragma unroll
    for (int mt = 0; mt < 4; ++mt)
#pragma unroll
        for (int r = 0; r < 4; ++r) { minv[mt][r] = INFINITY; mini[mt][r] = 0; }

    __syncthreads();   // tile0 DMA + Lyn writes visible

    int cur = 0;
    for (int tt = 0; tt < NT; ++tt) {
        const _Float16* LH = cur ? LdsH1 : LdsH0;
        const _Float16* LL = cur ? LdsL1 : LdsL0;
        _Float16* dH = cur ? LdsH0 : LdsH1;
        _Float16* dL = cur ? LdsL0 : LdsL1;
        const size_t gsnext = (size_t)((cbase0 + (tt + 1) * TILE_C) >> 4) * 1024;
        const int c0 = tt * TILE_C;
        const bool stg = (tt + 1 < NT);

#pragma unroll
        for (int ct = 0; ct < 4; ++ct) {
            // --- phase ct: (1) ds_read this ct's B fragments ---
            const int chunk0 = (wy * 4 + ct) * 128 + lane;   // 64 consecutive chunks/wave
            half8 bh0 = *(const half8*)(LH + (size_t)chunk0 * 8);
            half8 bl0 = *(const half8*)(LL + (size_t)chunk0 * 8);
            half8 bh1 = *(const half8*)(LH + (size_t)(chunk0 + 64) * 8);
            half8 bl1 = *(const half8*)(LL + (size_t)(chunk0 + 64) * 8);

            // --- (2) issue this phase's share of tile tt+1 staging (2 DMAs) ---
            if (stg) {
                const int jw = ct * 256 + wid * 64;
                gl2lds16(Wh + gsnext + (size_t)(jw + lane) * 8, dH + (size_t)jw * 8);
                gl2lds16(Wl + gsnext + (size_t)(jw + lane) * 8, dL + (size_t)jw * 8);
            }

            // --- (3) barrier between issue and wait: other waves' MFMA
            //     clusters cover this wave's ds_read latency ---
            __builtin_amdgcn_sched_barrier(0);
            __builtin_amdgcn_s_barrier();
            asm volatile("s_waitcnt lgkmcnt(0)" ::: "memory");
            __builtin_amdgcn_sched_barrier(0);   // rule #18: pin MFMA after wait

            // --- (4) MFMA cluster under raised priority ---
            const int   ccol = wy * 64 + ct * 16;
            const float yn   = Lyn[c0 + ccol + l15];
            const f32x4 yn4  = {yn, yn, yn, yn};             // acc init = yn
            f32x4 acc[4];
            __builtin_amdgcn_s_setprio(1);
#pragma unroll
            for (int mt = 0; mt < 4; ++mt) {
                // 3-term x (-2) with yn-init: acc ends as dist directly
                f32x4 a = __builtin_amdgcn_mfma_f32_16x16x32_f16(al[mt][0], bh0, yn4, 0, 0, 0);
                a = __builtin_amdgcn_mfma_f32_16x16x32_f16(ah[mt][0], bl0, a, 0, 0, 0);
                a = __builtin_amdgcn_mfma_f32_16x16x32_f16(ah[mt][0], bh0, a, 0, 0, 0);
                a = __builtin_amdgcn_mfma_f32_16x16x32_f16(al[mt][1], bh1, a, 0, 0, 0);
                a = __builtin_amdgcn_mfma_f32_16x16x32_f16(ah[mt][1], bl1, a, 0, 0, 0);
                a = __builtin_amdgcn_mfma_f32_16x16x32_f16(ah[mt][1], bh1, a, 0, 0, 0);
                acc[mt] = a;
            }
            __builtin_amdgcn_s_setprio(0);

            // --- (5) epilogue: acc IS dist; running argmin (c asc, strict <) ---
            const int cidx = cbase0 + c0 + ccol + l15;
#pragma unroll
            for (int mt = 0; mt < 4; ++mt) {
#pragma unroll
                for (int r = 0; r < 4; ++r) {
                    float s = acc[mt][r];
                    if (s < minv[mt][r]) { minv[mt][r] = s; mini[mt][r] = cidx; }
                }
            }
            __builtin_amdgcn_s_barrier();   // phase close
        }

        // --- tile boundary: drain tile tt+1's DMAs (2-deep forces vmcnt 0;
        //     they had the whole tile's 4 phases to land) ---
        asm volatile("s_waitcnt vmcnt(0)" ::: "memory");
        __builtin_amdgcn_s_barrier();
        cur ^= 1;
    }

    // --- cross-lane: reduce over the 16 col-lanes (xor on low 4 lane bits) ---
#pragma unroll
    for (int mt = 0; mt < 4; ++mt) {
#pragma unroll
        for (int r = 0; r < 4; ++r) {
            float v = minv[mt][r];
            int   i = mini[mt][r];
#pragma unroll
            for (int m = 1; m <= 8; m <<= 1) {
                float ov = __shfl_xor(v, m, 64);
                int   oi = __shfl_xor(i, m, 64);
                if (ov < v || (ov == v && oi < i)) { v = ov; i = oi; }
            }
            if (l15 == 0) {
                int qoff = wq * 64 + mt * 16 + lq * 4 + r;   // row within block
                RedV[wy][qoff] = v;
                RedI[wy][qoff] = i;
            }
        }
    }
    __syncthreads();

    // --- combine c-halves, then FENCE-FREE cross-split combine via atomics ---
    if (t < BQ) {
        float v0 = RedV[0][t]; int i0 = RedI[0][t];
        float v1 = RedV[1][t]; int i1 = RedI[1][t];
        if (v1 < v0 || (v1 == v0 && i1 < i0)) { v0 = v1; i0 = i1; }
        atomicMin(&packed[qblk + t], pack_di(v0, i0));   // device-scope, coherent
    }
    // ensure this block's atomicMins are globally performed before the ticket
    asm volatile("s_waitcnt vmcnt(0)" ::: "memory");
    __syncthreads();
    if (t == 0) fin = (atomicAdd(&cnt[bx], 1) == CSPLIT - 1);
    __syncthreads();
    if (fin && t < BQ) {
        // atomic read-back (atomicMin with identity) -> final packed value
        unsigned long long v = atomicMin(&packed[qblk + t], ~0ull);
        out[qblk + t] = (int)(unsigned int)(v & 0xFFFFFFFFu);
    }
}

// ---------------------------------------------------------------------------
extern "C" void kernel_launch(void* const* d_in, const int* in_sizes, int n_in,
                              void* d_out, int out_size, void* d_ws, size_t ws_size,
                              hipStream_t stream) {
    const float* X = (const float*)d_in[0];   // [16384, 64]
    const float* W = (const float*)d_in[1];   // [8192, 64]

    // ws layout: Wh(1MB) | Wl(1MB) | ynorm(32KB) | packed(128KB) | cnt(512B)
    _Float16* Wh    = (_Float16*)d_ws;
    _Float16* Wl    = Wh + (size_t)NTOK * EMB;
    float*    ynorm = (float*)(Wl + (size_t)NTOK * EMB);
    unsigned long long* packed = (unsigned long long*)(ynorm + NTOK);
    int*      cnt   = (int*)(packed + NQ);
    int*      out   = (int*)d_out;

    prep_kernel<<<(NTOK * 8) / TPB, TPB, 0, stream>>>(W, Wh, Wl, ynorm, packed, cnt);
    dim3 grid(NXBLK, CSPLIT);
    vq_mfma_kernel<<<grid, TPB, 0, stream>>>(X, Wh, Wl, ynorm, packed, cnt, out);
}

// Round 16
// 108.236 us; speedup vs baseline: 1.1178x; 1.0313x over previous
//
#include <hip/hip_runtime.h>
#include <math.h>

// Problem: X[16384,64] fp32, W[8192,64] fp32 -> argmin_c ||x-w_c||^2 (int32)
// FINAL (session-best, r12 configuration): total 108.2us (from 155.6 baseline).
// Main kernel ~62us vs 24.8us MFMA floor (3-term @ 2075 TF ubench);
// ~47us of total is fixed harness overhead (invariant across 1-4 dispatches).
#define EMB     64
#define NTOK    8192
#define NQ      16384
#define TPB     256               // 4 waves: 2 q-halves x 2 c-halves
#define CSPLIT  4
#define CRANGE  (NTOK / CSPLIT)   // 2048 codewords per y-split
#define BQ      128               // query rows per block
#define TILE_C  128               // codewords staged in LDS per iteration
#define NT      (CRANGE / TILE_C) // 16 tiles
#define TCH     (TILE_C * EMB)    // halves per tile buffer (8192 = 16KB)
#define NXBLK   (NQ / BQ)         // 128

typedef _Float16 half8 __attribute__((ext_vector_type(8)));
typedef float    f32x4 __attribute__((ext_vector_type(4)));

// async global->LDS DMA, 16B per lane (dest = wave-uniform base + lane*16)
__device__ __forceinline__ void gl2lds16(const _Float16* g, _Float16* l) {
    __builtin_amdgcn_global_load_lds(
        (const __attribute__((address_space(1))) unsigned int*)g,
        (__attribute__((address_space(3))) unsigned int*)l, 16, 0, 0);
}

// monotone float->uint map: m(a) < m(b) iff a < b (no NaNs here)
__device__ __forceinline__ unsigned long long pack_di(float d, int idx) {
    unsigned int u = __float_as_uint(d);
    unsigned int m = (u & 0x80000000u) ? ~u : (u | 0x80000000u);
    return ((unsigned long long)m << 32) | (unsigned int)idx;
}

// ---------------------------------------------------------------------------
// Prep v3 (verified r11/r12) -- COALESCED. One thread per input 8-float
// segment (65536 threads): reads row c = gtid>>3, seg = gtid&7 (wave covers
// contiguous 2KB). Writes Wh/Wl in 16x16 MFMA-FRAGMENT ORDER:
//   chunk u = g*128 + kb*64 + lq*16 + r holds W[g*16+r][kb*32+lq*8..+7].
// ynorm via 3-step shfl_xor tree over the 8 same-row lanes.
// Also inits packed[]/cnt[].
// ---------------------------------------------------------------------------
__global__ void prep_kernel(const float* __restrict__ W,
                            _Float16* __restrict__ Wh, _Float16* __restrict__ Wl,
                            float* __restrict__ ynorm,
                            unsigned long long* __restrict__ packed,
                            int* __restrict__ cnt) {
    const int gtid = blockIdx.x * blockDim.x + threadIdx.x;   // 0..65535
    if (gtid < NQ)    packed[gtid] = ~0ull;
    if (gtid < NXBLK) cnt[gtid] = 0;

    const int c   = gtid >> 3;          // input row (0..8191)
    const int seg = gtid & 7;           // 8-float segment within row
    const float* wp = W + (size_t)c * EMB + seg * 8;
    float4 v0 = *(const float4*)wp;     // coalesced: wave covers 2KB contiguous
    float4 v1 = *(const float4*)(wp + 4);
    float xv[8] = {v0.x, v0.y, v0.z, v0.w, v1.x, v1.y, v1.z, v1.w};
    half8 h, l;
    float s8 = 0.f;
#pragma unroll
    for (int j = 0; j < 8; ++j) {
        _Float16 hh = (_Float16)xv[j];
        h[j] = hh;
        l[j] = (_Float16)(xv[j] - (float)hh);
        s8 = fmaf(xv[j], xv[j], s8);
    }
    const int g = c >> 4, r = c & 15, kb = seg >> 2, lq = seg & 3;
    const size_t u = (size_t)g * 128 + kb * 64 + lq * 16 + r;
    *(half8*)(Wh + u * 8) = h;
    *(half8*)(Wl + u * 8) = l;

    // ynorm: tree-sum the 8 segment partials of row c (lanes 8-aligned)
    s8 += __shfl_xor(s8, 1, 64);
    s8 += __shfl_xor(s8, 2, 64);
    s8 += __shfl_xor(s8, 4, 64);
    if (seg == 0) ynorm[c] = s8;
}

// ---------------------------------------------------------------------------
// Main (r12, session best): fp16 3-TERM split MFMA distance + argmin.
// - 3-term: dot ~= ah*bh + ah*bl + al*bh (al*bl dropped, 2^-22 class).
// - -2 PRESCALE on A (exact exponent shift) + yn-fold acc-init: the MFMA
//   chain emits dist directly; epilogue is cmp+select only.
// - 2-phase async-DMA pipeline: STAGE(t+1) via global_load_lds under
//   COMPUTE(t); vmcnt(0)+lgkmcnt(0)+s_barrier per tile.
// - fence-free atomic combine (atomicMin on packed (dist,idx) u64).
// Session ablation ledger (all measured, 15 rounds -- do not regress):
//  - sync structure: drain+barrier / counted-wait / barrier-free private-LDS
//    / fine-phase+setprio (r6/r7/r8/r15) -- ALL ~62-66us. Not the bind.
//  - occupancy: 4 waves/SIMD worse in 3 geometries (r3/r10/r13).
//  - 32x32 MFMA shape: worse (r14, 77.5us -- less chain ILP).
//  - coop grid.sync fusion 3x slower (r4); __threadfence finisher +34us (r5).
//  - __launch_bounds__ arg2: (256,3)->cap 170 ok; >=4 waves/SIMD -> 64 VGPR
//    = total spill (r2, r9).
//  - Structural constraint: 51.5 GFLOP MFMA at 2075 TF = 24.8us floor;
//    main is 2.5x floor with ~62% idle INVARIANT to schedule -- the K=64
//    shape lacks the deep-K pipelining the 8-phase escape requires.
//    ~47us of dur_us is fixed harness overhead.
// ---------------------------------------------------------------------------
__global__ __launch_bounds__(TPB, 3) void vq_mfma_kernel(
    const float* __restrict__ X,
    const _Float16* __restrict__ Wh, const _Float16* __restrict__ Wl,
    const float* __restrict__ ynorm,
    unsigned long long* __restrict__ packed,
    int* __restrict__ cnt, int* __restrict__ out)
{
    __shared__ __align__(16) _Float16 LdsH0[TCH];
    __shared__ __align__(16) _Float16 LdsH1[TCH];
    __shared__ __align__(16) _Float16 LdsL0[TCH];
    __shared__ __align__(16) _Float16 LdsL1[TCH];
    __shared__ __align__(16) float    Lyn[CRANGE];
    __shared__ float RedV[2][BQ];
    __shared__ int   RedI[2][BQ];
    __shared__ int   fin;

    const int t    = threadIdx.x;
    const int lane = t & 63;
    const int wid  = t >> 6;       // 0..3
    const int wq   = wid & 1;      // q half (0/1)
    const int wy   = wid >> 1;     // c half (0/1)
    const int l15  = lane & 15;
    const int lq   = lane >> 4;    // 0..3

    const int bx     = blockIdx.x;
    const int qblk   = bx * BQ;
    const int qbase  = qblk + wq * 64;
    const int cbase0 = blockIdx.y * CRANGE;

    // --- issue tile-0 DMA first so it overlaps prologue work ---
    {
        const size_t gsbase = (size_t)(cbase0 >> 4) * 1024;   // halves
#pragma unroll
        for (int i = 0; i < 4; ++i) {
            const int jw = i * 256 + wid * 64;                // wave-uniform chunk base
            gl2lds16(Wh + gsbase + (size_t)(jw + lane) * 8, LdsH0 + (size_t)jw * 8);
            gl2lds16(Wl + gsbase + (size_t)(jw + lane) * 8, LdsL0 + (size_t)jw * 8);
        }
    }

    // --- stage the block's full ynorm range once ---
    for (int u = t; u < CRANGE / 4; u += TPB)
        ((float4*)Lyn)[u] = ((const float4*)(ynorm + cbase0))[u];

    // --- A fragments PRE-SCALED by -2 (exact): X rows (qbase + mt*16 + l15),
    //     k = kb*32 + lq*8 + j. Products become -2*x*w; acc init = yn. ---
    half8 ah[4][2], al[4][2];
#pragma unroll
    for (int mt = 0; mt < 4; ++mt) {
#pragma unroll
        for (int kb = 0; kb < 2; ++kb) {
            const float* xp = X + (size_t)(qbase + mt * 16 + l15) * EMB + kb * 32 + lq * 8;
            float4 v0 = *(const float4*)xp;
            float4 v1 = *(const float4*)(xp + 4);
            float xv[8] = {v0.x, v0.y, v0.z, v0.w, v1.x, v1.y, v1.z, v1.w};
            half8 h, l;
#pragma unroll
            for (int j = 0; j < 8; ++j) {
                _Float16 hh = (_Float16)xv[j];               // hi split (unscaled)
                float    rr = xv[j] - (float)hh;             // exact residual
                h[j] = (_Float16)(-2.0f * (float)hh);        // exact x2 scale
                l[j] = (_Float16)(-2.0f * rr);               // exact x2 scale
            }
            ah[mt][kb] = h;
            al[mt][kb] = l;
        }
    }

    float minv[4][4];
    int   mini[4][4];
#pragma unroll
    for (int mt = 0; mt < 4; ++mt)
#pragma unroll
        for (int r = 0; r < 4; ++r) { minv[mt][r] = INFINITY; mini[mt][r] = 0; }

    __syncthreads();   // tile0 DMA + Lyn writes visible

    int cur = 0;
    for (int tt = 0; tt < NT; ++tt) {
        // --- STAGE tile tt+1 into the other buffer (async DMA, in flight under MFMAs) ---
        if (tt + 1 < NT) {
            const size_t gsbase = (size_t)((cbase0 + (tt + 1) * TILE_C) >> 4) * 1024;
            _Float16* dH = (cur ^ 1) ? LdsH1 : LdsH0;
            _Float16* dL = (cur ^ 1) ? LdsL1 : LdsL0;
#pragma unroll
            for (int i = 0; i < 4; ++i) {
                const int jw = i * 256 + wid * 64;
                gl2lds16(Wh + gsbase + (size_t)(jw + lane) * 8, dH + (size_t)jw * 8);
                gl2lds16(Wl + gsbase + (size_t)(jw + lane) * 8, dL + (size_t)jw * 8);
            }
        }

        // --- COMPUTE tile tt from buf cur ---
        const _Float16* LH = cur ? LdsH1 : LdsH0;
        const _Float16* LL = cur ? LdsL1 : LdsL0;
        const int c0 = tt * TILE_C;
#pragma unroll
        for (int ct = 0; ct < 4; ++ct) {
            const int chunk0 = (wy * 4 + ct) * 128 + lane;   // 64 consecutive chunks/wave
            const int ccol   = wy * 64 + ct * 16;
            const float yn   = Lyn[c0 + ccol + l15];         // col depends on l15 only
            const f32x4 yn4  = {yn, yn, yn, yn};             // acc init = yn (D: col=lane&15)
            half8 bh0 = *(const half8*)(LH + (size_t)chunk0 * 8);
            half8 bl0 = *(const half8*)(LL + (size_t)chunk0 * 8);
            half8 bh1 = *(const half8*)(LH + (size_t)(chunk0 + 64) * 8);
            half8 bl1 = *(const half8*)(LL + (size_t)(chunk0 + 64) * 8);
            f32x4 acc[4];
#pragma unroll
            for (int mt = 0; mt < 4; ++mt) {
                // 3-term x (-2) with yn-init: acc ends as dist directly
                f32x4 a = __builtin_amdgcn_mfma_f32_16x16x32_f16(al[mt][0], bh0, yn4, 0, 0, 0);
                a = __builtin_amdgcn_mfma_f32_16x16x32_f16(ah[mt][0], bl0, a, 0, 0, 0);
                a = __builtin_amdgcn_mfma_f32_16x16x32_f16(ah[mt][0], bh0, a, 0, 0, 0);
                a = __builtin_amdgcn_mfma_f32_16x16x32_f16(al[mt][1], bh1, a, 0, 0, 0);
                a = __builtin_amdgcn_mfma_f32_16x16x32_f16(ah[mt][1], bl1, a, 0, 0, 0);
                a = __builtin_amdgcn_mfma_f32_16x16x32_f16(ah[mt][1], bh1, a, 0, 0, 0);
                acc[mt] = a;
            }
            // --- epilogue: acc IS dist; running argmin (c ascending, strict <) ---
            const int cidx = cbase0 + c0 + ccol + l15;
#pragma unroll
            for (int mt = 0; mt < 4; ++mt) {
#pragma unroll
                for (int r = 0; r < 4; ++r) {
                    float s = acc[mt][r];
                    if (s < minv[mt][r]) { minv[mt][r] = s; mini[mt][r] = cidx; }
                }
            }
        }

        // --- drain: tile tt+1 DMA has been landing under the MFMAs above ---
        asm volatile("s_waitcnt vmcnt(0)" ::: "memory");
        asm volatile("s_waitcnt lgkmcnt(0)" ::: "memory");
        __builtin_amdgcn_s_barrier();
        cur ^= 1;
    }

    // --- cross-lane: reduce over the 16 col-lanes (xor on low 4 lane bits) ---
#pragma unroll
    for (int mt = 0; mt < 4; ++mt) {
#pragma unroll
        for (int r = 0; r < 4; ++r) {
            float v = minv[mt][r];
            int   i = mini[mt][r];
#pragma unroll
            for (int m = 1; m <= 8; m <<= 1) {
                float ov = __shfl_xor(v, m, 64);
                int   oi = __shfl_xor(i, m, 64);
                if (ov < v || (ov == v && oi < i)) { v = ov; i = oi; }
            }
            if (l15 == 0) {
                int qoff = wq * 64 + mt * 16 + lq * 4 + r;   // row within block
                RedV[wy][qoff] = v;
                RedI[wy][qoff] = i;
            }
        }
    }
    __syncthreads();

    // --- combine c-halves, then FENCE-FREE cross-split combine via atomics ---
    if (t < BQ) {
        float v0 = RedV[0][t]; int i0 = RedI[0][t];
        float v1 = RedV[1][t]; int i1 = RedI[1][t];
        if (v1 < v0 || (v1 == v0 && i1 < i0)) { v0 = v1; i0 = i1; }
        atomicMin(&packed[qblk + t], pack_di(v0, i0));   // device-scope, coherent
    }
    // ensure this block's atomicMins are globally performed before the ticket
    asm volatile("s_waitcnt vmcnt(0)" ::: "memory");
    __syncthreads();
    if (t == 0) fin = (atomicAdd(&cnt[bx], 1) == CSPLIT - 1);
    __syncthreads();
    if (fin && t < BQ) {
        // atomic read-back (atomicMin with identity) -> final packed value
        unsigned long long v = atomicMin(&packed[qblk + t], ~0ull);
        out[qblk + t] = (int)(unsigned int)(v & 0xFFFFFFFFu);
    }
}

// ---------------------------------------------------------------------------
extern "C" void kernel_launch(void* const* d_in, const int* in_sizes, int n_in,
                              void* d_out, int out_size, void* d_ws, size_t ws_size,
                              hipStream_t stream) {
    const float* X = (const float*)d_in[0];   // [16384, 64]
    const float* W = (const float*)d_in[1];   // [8192, 64]

    // ws layout: Wh(1MB) | Wl(1MB) | ynorm(32KB) | packed(128KB) | cnt(512B)
    _Float16* Wh    = (_Float16*)d_ws;
    _Float16* Wl    = Wh + (size_t)NTOK * EMB;
    float*    ynorm = (float*)(Wl + (size_t)NTOK * EMB);
    unsigned long long* packed = (unsigned long long*)(ynorm + NTOK);
    int*      cnt   = (int*)(packed + NQ);
    int*      out   = (int*)d_out;

    prep_kernel<<<(NTOK * 8) / TPB, TPB, 0, stream>>>(W, Wh, Wl, ynorm, packed, cnt);
    dim3 grid(NXBLK, CSPLIT);
    vq_mfma_kernel<<<grid, TPB, 0, stream>>>(X, Wh, Wl, ynorm, packed, cnt, out);
}